// Round 7
// baseline (392.227 us; speedup 1.0000x reference)
//
#include <hip/hip_runtime.h>
#include <math.h>

// Problem constants (fixed by setup_inputs: B=16,K=32,L=1024,D=128,NEW_L=48)
constexpr int CB = 16, CK = 32, CL = 1024, CD = 128, CNL = 48;

// Native clang vector types (required by __builtin_nontemporal_*).
typedef float f32x4 __attribute__((ext_vector_type(4)));
typedef float f32x2 __attribute__((ext_vector_type(2)));

// Output offsets (floats), concat order:
// new_h0 (B,K,NL,D), new_event_time (B,K,NL), new_pad_mask (B,K,NL), almat (B,K,L,NL)
constexpr size_t OUT_H0 = 0;
constexpr size_t OUT_ET = (size_t)CB * CK * CNL * CD;      // 3,145,728
constexpr size_t OUT_PM = OUT_ET + (size_t)CB * CK * CNL;  // +24,576
constexpr size_t OUT_AL = OUT_PM + (size_t)CB * CK * CNL;  // +24,576

__global__ __launch_bounds__(512) void fused_kernel(
    const float* __restrict__ h0, const float* __restrict__ et,
    const float* __restrict__ npm, float* __restrict__ out) {
    __shared__ int segl[CL];           // 4 KB: seg id per row
    __shared__ int list[CL];           // 4 KB: row ids grouped by seg
    __shared__ int icnt[CNL + 1];      // per-seg row count (slot 48 = invalid dump)
    __shared__ int offs[CNL + 2];      // exclusive prefix of icnt
    __shared__ int fill[CNL + 1];      // scatter cursors
    __shared__ float ts_s[CNL + 1];
    __shared__ float ms_s[CNL + 1];

    const int bk = blockIdx.x;
    const int b = bk >> 5;
    const int t = threadIdx.x;

    if (t < CNL + 1) { icnt[t] = 0; fill[t] = 0; ts_s[t] = 0.f; ms_s[t] = 0.f; }
    __syncthreads();

    // ---- Phase 1: seg ids + histograms (counts, tsum, msum) ----
    {
        const float2 e2 = ((const float2*)(et + b * CL))[t];
        const float2 m2 = ((const float2*)(npm + (size_t)bk * CL))[t];
        const int l0 = 2 * t;
        bool va = (e2.x >= 0.f) && (e2.x < (float)CNL);
        bool vb = (e2.y >= 0.f) && (e2.y < (float)CNL);
        int sa = va ? (int)e2.x : CNL;   // trunc == floor for x >= 0
        int sb = vb ? (int)e2.y : CNL;
        segl[l0] = sa;
        segl[l0 + 1] = sb;
        atomicAdd(&icnt[sa], 1);
        atomicAdd(&icnt[sb], 1);
        if (va) atomicAdd(&ts_s[sa], e2.x);
        if (vb) atomicAdd(&ts_s[sb], e2.y);
        atomicAdd(&ms_s[sa], m2.x);      // slot CNL is a dump for invalid
        atomicAdd(&ms_s[sb], m2.y);
    }
    __syncthreads();

    // ---- Phase 2: exclusive prefix over 49 bins (serial, trivial) ----
    if (t == 0) {
        int acc = 0;
        for (int s = 0; s <= CNL; ++s) { offs[s] = acc; acc += icnt[s]; }
        offs[CNL + 1] = acc;
    }
    __syncthreads();

    // ---- Phase 3: scatter row ids grouped by segment ----
    {
        const int l0 = 2 * t;
        const int sa = segl[l0], sb = segl[l0 + 1];
        int pa = atomicAdd(&fill[sa], 1);
        list[offs[sa] + pa] = l0;
        int pb = atomicAdd(&fill[sb], 1);
        list[offs[sb] + pb] = l0 + 1;
    }
    __syncthreads();

    // ---- almat (b,k,l,new_l): issued EARLY; nt streaming stores drain
    // under the read-heavy max phase. 12288 float4 per block, coalesced.
    {
        f32x4* oa = (f32x4*)(out + OUT_AL + (size_t)bk * CL * CNL);
#pragma unroll
        for (int i = 0; i < 24; ++i) {
            const int idx = t + i * 512;
            const int row = idx / 12;
            const int c4 = idx - row * 12;
            const int s = segl[row];
            const int c = c4 * 4;
            f32x4 v;
            v.x = (c + 0 == s) ? 1.f : 0.f;
            v.y = (c + 1 == s) ? 1.f : 0.f;
            v.z = (c + 2 == s) ? 1.f : 0.f;
            v.w = (c + 3 == s) ? 1.f : 0.f;
            __builtin_nontemporal_store(v, &oa[idx]);
        }
    }

    // ---- Phase 4: segment-max. One wave owns one segment at a time:
    // lane holds 2 columns in registers; inner loop is pure load+fmax
    // (no LDS atomics -> loads pipeline deeply). Writes results direct
    // to global with the counts<L clamp applied.
    const float* hb = h0 + (size_t)bk * CL * CD;
    float* oh = out + OUT_H0 + (size_t)bk * CNL * CD;
    const int wid = t >> 6;              // wave 0..7
    const int lane = t & 63;
    const int d0 = lane * 2;             // lane's 2 columns
    for (int s = wid; s < CNL; s += 8) {
        const int beg = offs[s];
        const int end = offs[s + 1];
        float vx = -__builtin_inff(), vy = -__builtin_inff();
        int i = beg;
        for (; i + 4 <= end; i += 4) {
            const int r0 = list[i + 0];
            const int r1 = list[i + 1];
            const int r2 = list[i + 2];
            const int r3 = list[i + 3];
            const f32x2 v0 = __builtin_nontemporal_load(
                (const f32x2*)(hb + (size_t)r0 * CD + d0));
            const f32x2 v1 = __builtin_nontemporal_load(
                (const f32x2*)(hb + (size_t)r1 * CD + d0));
            const f32x2 v2 = __builtin_nontemporal_load(
                (const f32x2*)(hb + (size_t)r2 * CD + d0));
            const f32x2 v3 = __builtin_nontemporal_load(
                (const f32x2*)(hb + (size_t)r3 * CD + d0));
            vx = fmaxf(fmaxf(fmaxf(fmaxf(vx, v0.x), v1.x), v2.x), v3.x);
            vy = fmaxf(fmaxf(fmaxf(fmaxf(vy, v0.y), v1.y), v2.y), v3.y);
        }
        for (; i < end; ++i) {
            const int r = list[i];
            const f32x2 v = __builtin_nontemporal_load(
                (const f32x2*)(hb + (size_t)r * CD + d0));
            vx = fmaxf(vx, v.x);
            vy = fmaxf(vy, v.y);
        }
        // include_zero: counts < L  (end-beg == valid count for s < CNL)
        if (end - beg < CL) { vx = fmaxf(vx, 0.f); vy = fmaxf(vy, 0.f); }
        f32x2 o;
        o.x = vx;
        o.y = vy;
        __builtin_nontemporal_store(o, (f32x2*)(oh + s * CD + d0));
    }

    // ---- small outputs ----
    if (t < CNL) {
        const float den = fmaxf((float)icnt[t], 1.f);
        out[OUT_ET + (size_t)bk * CNL + t] = ts_s[t] / den;
        out[OUT_PM + (size_t)bk * CNL + t] = ms_s[t] / den;
    }
}

extern "C" void kernel_launch(void* const* d_in, const int* in_sizes, int n_in,
                              void* d_out, int out_size, void* d_ws, size_t ws_size,
                              hipStream_t stream) {
    (void)in_sizes; (void)n_in; (void)out_size; (void)d_ws; (void)ws_size;
    const float* h0  = (const float*)d_in[0];
    const float* et  = (const float*)d_in[1];
    const float* npm = (const float*)d_in[2];
    // d_in[3] = new_l (48, hardcoded)
    float* out = (float*)d_out;

    fused_kernel<<<CB * CK, 512, 0, stream>>>(h0, et, npm, out);
}